// Round 5
// baseline (237.534 us; speedup 1.0000x reference)
//
#include <hip/hip_runtime.h>
#include <hip/hip_bf16.h>
#include <stdint.h>

typedef __bf16 bf16_t;
typedef __attribute__((ext_vector_type(8))) __bf16 bf16x8;
typedef __attribute__((ext_vector_type(4))) __bf16 bf16x4;
typedef __attribute__((ext_vector_type(4))) float f32x4;

static constexpr int T_SEQ = 2048;
static constexpr int HID   = 2048;
static constexpr int NHEAD = 32;
static constexpr int NKVH  = 8;
static constexpr int HDIM  = 64;
static constexpr int QKVD  = 3072;   // 64*(32+16)

__device__ inline f32x4 mfma16(bf16x8 a, bf16x8 b, f32x4 c) {
    return __builtin_amdgcn_mfma_f32_16x16x32_bf16(a, b, c, 0, 0, 0);
}

__device__ inline void load_lds16(const bf16_t* g, bf16_t* l) {
    __builtin_amdgcn_global_load_lds(
        (const __attribute__((address_space(1))) void*)g,
        (__attribute__((address_space(3))) void*)l, 16, 0, 0);
}

// ---------------- prep: fused weight transposes + RMSNorm (one dispatch) ----------------
// blocks [0,1536): Wq transpose; [1536,2560): Wo transpose; [2560,4608): rmsnorm rows.
__global__ __launch_bounds__(256) void prep_kernel(const float* __restrict__ Wq,
                                                   const float* __restrict__ Wo,
                                                   bf16_t* __restrict__ Tq,
                                                   bf16_t* __restrict__ To,
                                                   const float* __restrict__ x,
                                                   const float* __restrict__ scale,
                                                   bf16_t* __restrict__ normed) {
    __shared__ float tile[64 * 65];   // 16.6 KB (also hosts rmsnorm partials)
    int b = blockIdx.x;
    const int t = threadIdx.x;
    if (b < 2560) {
        const float* in; bf16_t* out; int NN, KK, bx, by;
        if (b < 1536) { in = Wq; out = Tq; NN = QKVD; KK = HID; bx = b % 48; by = b / 48; }
        else { b -= 1536; in = Wo; out = To; NN = HID; KK = HID; bx = b % 32; by = b / 32; }
        const int c4 = (t & 15) * 4;
#pragma unroll
        for (int i = 0; i < 4; ++i) {
            int r = (t >> 4) + i * 16;
            float4 v = *(const float4*)(in + (size_t)(by*64 + r) * NN + bx*64 + c4);
            tile[r*65 + c4 + 0] = v.x; tile[r*65 + c4 + 1] = v.y;
            tile[r*65 + c4 + 2] = v.z; tile[r*65 + c4 + 3] = v.w;
        }
        __syncthreads();
        const int kc = t & 7;
#pragma unroll
        for (int i = 0; i < 2; ++i) {
            int n = (t >> 3) + i * 32;
            bf16x8 o;
#pragma unroll
            for (int j = 0; j < 8; ++j) o[j] = (bf16_t)tile[(kc*8 + j)*65 + n];
            *(bf16x8*)(out + (size_t)(bx*64 + n) * KK + by*64 + kc*8) = o;
        }
    } else {
        int row = b - 2560;
        const float4* x4 = (const float4*)(x + (size_t)row * HID);
        const float4* s4 = (const float4*)scale;
        float4 v0 = x4[t], v1 = x4[t + 256];
        float ss = v0.x*v0.x + v0.y*v0.y + v0.z*v0.z + v0.w*v0.w
                 + v1.x*v1.x + v1.y*v1.y + v1.z*v1.z + v1.w*v1.w;
#pragma unroll
        for (int off = 32; off > 0; off >>= 1) ss += __shfl_down(ss, off);
        if ((t & 63) == 0) tile[t >> 6] = ss;
        __syncthreads();
        float total = tile[0] + tile[1] + tile[2] + tile[3];
        float inv = rsqrtf(total * (1.0f / HID) + 1e-5f);
        float4 sc0 = s4[t], sc1 = s4[t + 256];
        bf16_t* outr = normed + (size_t)row * HID;
        bf16x4 o0, o1;
        o0.x = (bf16_t)(v0.x*inv*sc0.x); o0.y = (bf16_t)(v0.y*inv*sc0.y);
        o0.z = (bf16_t)(v0.z*inv*sc0.z); o0.w = (bf16_t)(v0.w*inv*sc0.w);
        o1.x = (bf16_t)(v1.x*inv*sc1.x); o1.y = (bf16_t)(v1.y*inv*sc1.y);
        o1.z = (bf16_t)(v1.z*inv*sc1.z); o1.w = (bf16_t)(v1.w*inv*sc1.w);
        *(bf16x4*)(outr + 4*t)        = o0;
        *(bf16x4*)(outr + 1024 + 4*t) = o1;
    }
}

// ---------------- split-K GEMM, 64x128 tile: Cpart[z][M][N](bf16) ----------------
// Grid: (N/128, M/64, 2). 6 blocks/CU for QKV, 4 for out-proj.
// XOR-swizzled DMA staging (round-2 verified): LDS chunk j holds global chunk
// (r=j>>2, c=(j&3)^((r>>1)&3)); fragment read offset (quad^((lm>>1)&3))*8.
__global__ __launch_bounds__(256) void gemm_splitk(const bf16_t* __restrict__ A,
                                                   const bf16_t* __restrict__ Bt,
                                                   bf16_t* __restrict__ Cpart,
                                                   int M, int N, int K) {
    __shared__ __align__(16) bf16_t Asm[64 * 32];    // 4 KB
    __shared__ __align__(16) bf16_t Bsm[128 * 32];   // 8 KB
    const int tid = threadIdx.x;
    const int bm = blockIdx.y * 64, bn = blockIdx.x * 128;
    const int kh = K >> 1;
    const int kb = blockIdx.z * kh;
    const int lane = tid & 63, wave = tid >> 6;
    const int wm = (wave & 1) * 32, wn = (wave >> 1) * 64;
    const int lm = lane & 15, quad = lane >> 4;

    f32x4 acc[2][4];
#pragma unroll
    for (int i = 0; i < 2; ++i)
#pragma unroll
        for (int j = 0; j < 4; ++j) acc[i][j] = (f32x4){0.f, 0.f, 0.f, 0.f};

    // A: 256 chunks, 1 per thread; B: 512 chunks, 2 per thread.
    const int cidA = wave * 64 + lane;
    const int rA = cidA >> 2, cA = (cidA & 3) ^ ((rA >> 1) & 3);
    const int cid0 = wave * 64 + lane;
    const int cid1 = cid0 + 256;
    const int r0 = cid0 >> 2, c0 = (cid0 & 3) ^ ((r0 >> 1) & 3);
    const int r1 = cid1 >> 2, c1 = (cid1 & 3) ^ ((r1 >> 1) & 3);
    const bf16_t* Ab = A  + (size_t)bm * K + kb;
    const bf16_t* Bb = Bt + (size_t)bn * K + kb;
    const size_t gaA = (size_t)rA * K + cA * 8;
    const size_t ga0 = (size_t)r0 * K + c0 * 8;
    const size_t ga1 = (size_t)r1 * K + c1 * 8;
    bf16_t* ldsA  = &Asm[wave * 512];
    bf16_t* ldsB0 = &Bsm[wave * 512];
    bf16_t* ldsB1 = &Bsm[2048 + wave * 512];

    const int swz = (quad ^ ((lm >> 1) & 3)) * 8;

    for (int k0 = 0; k0 < kh; k0 += 32) {
        load_lds16(Ab + gaA + k0, ldsA);
        load_lds16(Bb + ga0 + k0, ldsB0);
        load_lds16(Bb + ga1 + k0, ldsB1);
        __syncthreads();
        bf16x8 af[2], bfr[4];
#pragma unroll
        for (int i = 0; i < 2; ++i)
            af[i]  = *(const bf16x8*)&Asm[(wm + i*16 + lm)*32 + swz];
#pragma unroll
        for (int j = 0; j < 4; ++j)
            bfr[j] = *(const bf16x8*)&Bsm[(wn + j*16 + lm)*32 + swz];
#pragma unroll
        for (int i = 0; i < 2; ++i)
#pragma unroll
            for (int j = 0; j < 4; ++j) acc[i][j] = mfma16(af[i], bfr[j], acc[i][j]);
        __syncthreads();
    }

    bf16_t* Cp = Cpart + (size_t)blockIdx.z * M * N;
#pragma unroll
    for (int i = 0; i < 2; ++i) {
        int gr = bm + wm + i*16 + quad*4;
#pragma unroll
        for (int j = 0; j < 4; ++j) {
            int gc = bn + wn + j*16 + lm;
#pragma unroll
            for (int r = 0; r < 4; ++r)
                Cp[(size_t)(gr + r)*N + gc] = (bf16_t)acc[i][j][r];
        }
    }
}

// ---------------- combine partials + bias + rope (vectorized), scatter to Q/K/V ----------
__global__ __launch_bounds__(192) void rope_split(const bf16_t* __restrict__ qp0,
                                                  const bf16_t* __restrict__ qp1,
                                                  const float* __restrict__ qbias,
                                                  const float* __restrict__ cost,
                                                  const float* __restrict__ sint,
                                                  bf16_t* __restrict__ Qb,
                                                  bf16_t* __restrict__ Kb,
                                                  bf16_t* __restrict__ Vb) {
    const int t = blockIdx.x;
    const int hr = threadIdx.x >> 2, p0 = (threadIdx.x & 3) * 8;
    const bf16_t* r0 = qp0 + (size_t)t * QKVD + hr * 64;
    const bf16_t* r1 = qp1 + (size_t)t * QKVD + hr * 64;
    bf16x8 a1 = *(const bf16x8*)(r0 + p0);
    bf16x8 a2 = *(const bf16x8*)(r0 + p0 + 32);
    bf16x8 b1 = *(const bf16x8*)(r1 + p0);
    bf16x8 b2 = *(const bf16x8*)(r1 + p0 + 32);
    const float* qb = qbias + hr * 64;
    float x1[8], x2[8];
#pragma unroll
    for (int j = 0; j < 8; ++j) {
        x1[j] = (float)a1[j] + (float)b1[j] + qb[p0 + j];
        x2[j] = (float)a2[j] + (float)b2[j] + qb[p0 + j + 32];
    }
    bf16x8 w1, w2;
    if (hr < 40) {
        const float* c = cost + (size_t)t * 32 + p0;
        const float* s = sint + (size_t)t * 32 + p0;
#pragma unroll
        for (int j = 0; j < 8; ++j) {
            float cc = c[j], ss = s[j];
            w1[j] = (bf16_t)(x1[j]*cc - x2[j]*ss);
            w2[j] = (bf16_t)(x2[j]*cc + x1[j]*ss);
        }
    } else {
#pragma unroll
        for (int j = 0; j < 8; ++j) { w1[j] = (bf16_t)x1[j]; w2[j] = (bf16_t)x2[j]; }
    }
    bf16_t* dst;
    if (hr < 32)      dst = Qb + ((size_t)t*NHEAD + hr)      * HDIM;
    else if (hr < 40) dst = Kb + ((size_t)t*NKVH + (hr-32))  * HDIM;
    else              dst = Vb + ((size_t)t*NKVH + (hr-40))  * HDIM;
    *(bf16x8*)(dst + p0)      = w1;
    *(bf16x8*)(dst + p0 + 32) = w2;
}

// ---------------- combine out-proj partials + bias + residual ----------------
__global__ __launch_bounds__(256) void combine_out(const bf16_t* __restrict__ p0,
                                                   const bf16_t* __restrict__ p1,
                                                   const float* __restrict__ bias,
                                                   const float* __restrict__ x,
                                                   float* __restrict__ out) {
    const int n4 = T_SEQ * HID / 4;
    for (int i4 = blockIdx.x * 256 + threadIdx.x; i4 < n4; i4 += gridDim.x * 256) {
        bf16x4 a = *(const bf16x4*)(p0 + (size_t)i4 * 4);
        bf16x4 b = *(const bf16x4*)(p1 + (size_t)i4 * 4);
        float4 xv = *(const float4*)(x + (size_t)i4 * 4);
        int col4 = (i4 * 4) & (HID - 1);
        float4 bi = *(const float4*)(bias + col4);
        float4 o;
        o.x = (float)a.x + (float)b.x + bi.x + xv.x;
        o.y = (float)a.y + (float)b.y + bi.y + xv.y;
        o.z = (float)a.z + (float)b.z + bi.z + xv.z;
        o.w = (float)a.w + (float)b.w + bi.w + xv.w;
        *(float4*)(out + (size_t)i4 * 4) = o;
    }
}

// ---------------- attention (round-4 structure): direct global Q/K frags, one barrier -----
__global__ __launch_bounds__(256) void attn_kernel(const bf16_t* __restrict__ Qb,
                                                   const bf16_t* __restrict__ Kb,
                                                   const bf16_t* __restrict__ Vb,
                                                   const float* __restrict__ sinks,
                                                   bf16_t* __restrict__ attnb) {
    __shared__ __align__(16) bf16_t Vt[64 * 200];
    __shared__ __align__(16) bf16_t Ws[64 * 200];

    const int tid = threadIdx.x;
    const int qt = blockIdx.x, h = blockIdx.y;
    const int qs = qt * 64;
    const int nkv = h >> 2;

#pragma unroll
    for (int it = 0; it < 3; ++it) {
        int pu = tid + it * 256;
        int j = (pu >> 3) * 2, off = (pu & 7) * 8;
        int kg0 = qs - 128 + j; if (kg0 < 0) kg0 = 0;
        int kg1 = qs - 128 + j + 1; if (kg1 < 0) kg1 = 0;
        union { uint4 u; bf16_t e[8]; } v0, v1;
        v0.u = *(const uint4*)(Vb + ((size_t)kg0*NKVH + nkv)*HDIM + off);
        v1.u = *(const uint4*)(Vb + ((size_t)kg1*NKVH + nkv)*HDIM + off);
#pragma unroll
        for (int r = 0; r < 8; ++r) {
            union { uint u; bf16_t e[2]; } p;
            p.e[0] = v0.e[r]; p.e[1] = v1.e[r];
            *(uint*)&Vt[(off + r)*200 + j] = p.u;
        }
    }

    const int lane = tid & 63, wave = tid >> 6;
    const int lm = lane & 15, quad = lane >> 4;
    const int w16 = wave * 16;

    f32x4 S[12];
#pragma unroll
    for (int jt = 0; jt < 12; ++jt) S[jt] = (f32x4){0.f, 0.f, 0.f, 0.f};
    const bf16_t* Qrow = Qb + ((size_t)(qs + w16 + lm)*NHEAD + h)*HDIM + quad*8;
    int krow[12];
#pragma unroll
    for (int jt = 0; jt < 12; ++jt) {
        int kg = qs - 128 + jt*16 + lm;
        krow[jt] = kg < 0 ? 0 : kg;
    }
#pragma unroll
    for (int ks = 0; ks < 2; ++ks) {
        bf16x8 aq = *(const bf16x8*)(Qrow + ks*32);
#pragma unroll
        for (int jt = 0; jt < 12; ++jt) {
            bf16x8 bk = *(const bf16x8*)(Kb + ((size_t)krow[jt]*NKVH + nkv)*HDIM + ks*32 + quad*8);
            S[jt] = mfma16(aq, bk, S[jt]);
        }
    }

    const float sink = sinks[h];
#pragma unroll
    for (int reg = 0; reg < 4; ++reg) {
        const int qg = qs + w16 + quad*4 + reg;
        float mx = -1e30f;
#pragma unroll
        for (int jt = 0; jt < 12; ++jt) {
            int kg = qs - 128 + jt*16 + lm;
            float sv = S[jt][reg] * 0.125f;
            bool valid = (kg >= 0) && (kg <= qg) && (qg - kg <= 128);
            sv = valid ? sv : -1e30f;
            S[jt][reg] = sv;
            mx = fmaxf(mx, sv);
        }
#pragma unroll
        for (int off = 1; off < 16; off <<= 1) mx = fmaxf(mx, __shfl_xor(mx, off));
        float M = fmaxf(mx, sink);
        float sum = 0.f;
#pragma unroll
        for (int jt = 0; jt < 12; ++jt) {
            float e = __expf(S[jt][reg] - M);
            S[jt][reg] = e; sum += e;
        }
#pragma unroll
        for (int off = 1; off < 16; off <<= 1) sum += __shfl_xor(sum, off);
        float rden = 1.f / (sum + __expf(sink - M));
#pragma unroll
        for (int jt = 0; jt < 12; ++jt)
            Ws[(w16 + quad*4 + reg)*200 + jt*16 + lm] = (bf16_t)(S[jt][reg] * rden);
    }
    __syncthreads();

    f32x4 O[4];
#pragma unroll
    for (int nt = 0; nt < 4; ++nt) O[nt] = (f32x4){0.f, 0.f, 0.f, 0.f};
#pragma unroll
    for (int ks = 0; ks < 6; ++ks) {
        bf16x8 aw = *(const bf16x8*)&Ws[(w16 + lm)*200 + ks*32 + quad*8];
#pragma unroll
        for (int nt = 0; nt < 4; ++nt) {
            bf16x8 bv = *(const bf16x8*)&Vt[(nt*16 + lm)*200 + ks*32 + quad*8];
            O[nt] = mfma16(aw, bv, O[nt]);
        }
    }
#pragma unroll
    for (int nt = 0; nt < 4; ++nt)
#pragma unroll
        for (int reg = 0; reg < 4; ++reg)
            attnb[(size_t)(qs + w16 + quad*4 + reg)*HID + h*HDIM + nt*16 + lm] =
                (bf16_t)(O[nt][reg]);
}

// ---------------- launch ----------------
extern "C" void kernel_launch(void* const* d_in, const int* in_sizes, int n_in,
                              void* d_out, int out_size, void* d_ws, size_t ws_size,
                              hipStream_t stream) {
    (void)in_sizes; (void)n_in; (void)out_size; (void)ws_size;
    const float* x          = (const float*)d_in[0];
    const float* scale      = (const float*)d_in[1];
    const float* sinks      = (const float*)d_in[2];
    const float* qkv_kernel = (const float*)d_in[3];
    const float* qkv_bias   = (const float*)d_in[4];
    const float* out_kernel = (const float*)d_in[5];
    const float* out_bias   = (const float*)d_in[6];
    const float* cos_t      = (const float*)d_in[7];
    const float* sin_t      = (const float*)d_in[8];
    float* out = (float*)d_out;

    char* ws = (char*)d_ws;
    const size_t MiB = 1048576;
    bf16_t* Wt_out = (bf16_t*)(ws);
    bf16_t* Wt_qkv = (bf16_t*)(ws + 8*MiB);
    bf16_t* attnb  = (bf16_t*)(ws + 8*MiB);
    bf16_t* normed = (bf16_t*)(ws + 20*MiB);
    bf16_t* qkvp   = (bf16_t*)(ws + 28*MiB);
    bf16_t* outp   = (bf16_t*)(ws + 28*MiB);
    bf16_t* Qb     = (bf16_t*)(ws + 52*MiB);
    bf16_t* Kb     = (bf16_t*)(ws + 60*MiB);
    bf16_t* Vb     = (bf16_t*)(ws + 62*MiB);

    prep_kernel<<<4608, 256, 0, stream>>>(qkv_kernel, out_kernel, Wt_qkv, Wt_out,
                                          x, scale, normed);
    gemm_splitk<<<dim3(QKVD/128, T_SEQ/64, 2), 256, 0, stream>>>(normed, Wt_qkv, qkvp,
                                                                 T_SEQ, QKVD, HID);
    rope_split<<<T_SEQ, 192, 0, stream>>>(qkvp, qkvp + (size_t)T_SEQ*QKVD, qkv_bias,
                                          cos_t, sin_t, Qb, Kb, Vb);
    attn_kernel<<<dim3(T_SEQ/64, NHEAD), 256, 0, stream>>>(Qb, Kb, Vb, sinks, attnb);
    gemm_splitk<<<dim3(HID/128, T_SEQ/64, 2), 256, 0, stream>>>(attnb, Wt_out, outp,
                                                                T_SEQ, HID, HID);
    combine_out<<<2048, 256, 0, stream>>>(outp, outp + (size_t)T_SEQ*HID, out_bias, x, out);
}

// Round 6
// 231.154 us; speedup vs baseline: 1.0276x; 1.0276x over previous
//
#include <hip/hip_runtime.h>
#include <hip/hip_bf16.h>
#include <stdint.h>

typedef __bf16 bf16_t;
typedef __attribute__((ext_vector_type(8))) __bf16 bf16x8;
typedef __attribute__((ext_vector_type(4))) __bf16 bf16x4;
typedef __attribute__((ext_vector_type(4))) float f32x4;

static constexpr int T_SEQ = 2048;
static constexpr int HID   = 2048;
static constexpr int NHEAD = 32;
static constexpr int NKVH  = 8;
static constexpr int HDIM  = 64;
static constexpr int QKVD  = 3072;   // 64*(32+16)

__device__ inline f32x4 mfma16(bf16x8 a, bf16x8 b, f32x4 c) {
    return __builtin_amdgcn_mfma_f32_16x16x32_bf16(a, b, c, 0, 0, 0);
}

__device__ inline void load_lds16(const bf16_t* g, bf16_t* l) {
    __builtin_amdgcn_global_load_lds(
        (const __attribute__((address_space(1))) void*)g,
        (__attribute__((address_space(3))) void*)l, 16, 0, 0);
}

// ---------------- prep: weight transposes + RMSNorm + out-init (one dispatch) ------------
// blocks [0,1536): Wq transpose; [1536,2560): Wo transpose; [2560,4608): rmsnorm rows
// (rmsnorm branch also writes out = x + out_bias, the base for out-proj atomics).
__global__ __launch_bounds__(256) void prep_kernel(const float* __restrict__ Wq,
                                                   const float* __restrict__ Wo,
                                                   bf16_t* __restrict__ Tq,
                                                   bf16_t* __restrict__ To,
                                                   const float* __restrict__ x,
                                                   const float* __restrict__ scale,
                                                   bf16_t* __restrict__ normed,
                                                   const float* __restrict__ obias,
                                                   float* __restrict__ out) {
    __shared__ float tile[64 * 65];
    int b = blockIdx.x;
    const int t = threadIdx.x;
    if (b < 2560) {
        const float* in; bf16_t* outw; int NN, KK, bx, by;
        if (b < 1536) { in = Wq; outw = Tq; NN = QKVD; KK = HID; bx = b % 48; by = b / 48; }
        else { b -= 1536; in = Wo; outw = To; NN = HID; KK = HID; bx = b % 32; by = b / 32; }
        const int c4 = (t & 15) * 4;
#pragma unroll
        for (int i = 0; i < 4; ++i) {
            int r = (t >> 4) + i * 16;
            float4 v = *(const float4*)(in + (size_t)(by*64 + r) * NN + bx*64 + c4);
            tile[r*65 + c4 + 0] = v.x; tile[r*65 + c4 + 1] = v.y;
            tile[r*65 + c4 + 2] = v.z; tile[r*65 + c4 + 3] = v.w;
        }
        __syncthreads();
        const int kc = t & 7;
#pragma unroll
        for (int i = 0; i < 2; ++i) {
            int n = (t >> 3) + i * 32;
            bf16x8 o;
#pragma unroll
            for (int j = 0; j < 8; ++j) o[j] = (bf16_t)tile[(kc*8 + j)*65 + n];
            *(bf16x8*)(outw + (size_t)(bx*64 + n) * KK + by*64 + kc*8) = o;
        }
    } else {
        int row = b - 2560;
        const float4* x4 = (const float4*)(x + (size_t)row * HID);
        const float4* s4 = (const float4*)scale;
        const float4* b4 = (const float4*)obias;
        float4 v0 = x4[t], v1 = x4[t + 256];
        float ss = v0.x*v0.x + v0.y*v0.y + v0.z*v0.z + v0.w*v0.w
                 + v1.x*v1.x + v1.y*v1.y + v1.z*v1.z + v1.w*v1.w;
#pragma unroll
        for (int off = 32; off > 0; off >>= 1) ss += __shfl_down(ss, off);
        if ((t & 63) == 0) tile[t >> 6] = ss;
        __syncthreads();
        float total = tile[0] + tile[1] + tile[2] + tile[3];
        float inv = rsqrtf(total * (1.0f / HID) + 1e-5f);
        float4 sc0 = s4[t], sc1 = s4[t + 256];
        bf16_t* outr = normed + (size_t)row * HID;
        bf16x4 o0, o1;
        o0.x = (bf16_t)(v0.x*inv*sc0.x); o0.y = (bf16_t)(v0.y*inv*sc0.y);
        o0.z = (bf16_t)(v0.z*inv*sc0.z); o0.w = (bf16_t)(v0.w*inv*sc0.w);
        o1.x = (bf16_t)(v1.x*inv*sc1.x); o1.y = (bf16_t)(v1.y*inv*sc1.y);
        o1.z = (bf16_t)(v1.z*inv*sc1.z); o1.w = (bf16_t)(v1.w*inv*sc1.w);
        *(bf16x4*)(outr + 4*t)        = o0;
        *(bf16x4*)(outr + 1024 + 4*t) = o1;
        // out-init: out = x + out_bias (out-proj gemm atomically accumulates onto this)
        float4 bb0 = b4[t], bb1 = b4[t + 256];
        float4 oi0 = {v0.x + bb0.x, v0.y + bb0.y, v0.z + bb0.z, v0.w + bb0.w};
        float4 oi1 = {v1.x + bb1.x, v1.y + bb1.y, v1.z + bb1.z, v1.w + bb1.w};
        float* orow = out + (size_t)row * HID;
        *(float4*)(orow + 4*t)        = oi0;
        *(float4*)(orow + 1024 + 4*t) = oi1;
    }
}

// ---------------- split-K GEMM, 128x128 tile, BK=64 (two 32-k sub-tiles/barrier) ----------
// Each sub-tile uses the round-2 verified conflict-free geometry: LDS chunk j holds
// global chunk (r=j>>2, c=(j&3)^((r>>1)&3)); fragment read offset (quad^((lm>>1)&3))*8.
// ATOMIC=0: bf16 partials to Cpart[z][M][N].  ATOMIC=1: f32 atomicAdd into Cred (pre-inited).
template <int ATOMIC>
__global__ __launch_bounds__(256) void gemm_splitk(const bf16_t* __restrict__ A,
                                                   const bf16_t* __restrict__ Bt,
                                                   bf16_t* __restrict__ Cpart,
                                                   float* __restrict__ Cred,
                                                   int M, int N, int K) {
    __shared__ __align__(16) bf16_t Asm[2 * 128 * 32];   // 16 KB
    __shared__ __align__(16) bf16_t Bsm[2 * 128 * 32];   // 16 KB
    const int tid = threadIdx.x;
    const int bm = blockIdx.y * 128, bn = blockIdx.x * 128;
    const int kh = K >> 1;
    const int kb = blockIdx.z * kh;
    const int lane = tid & 63, wave = tid >> 6;
    const int wm = (wave & 1) * 64, wn = (wave >> 1) * 64;
    const int lm = lane & 15, quad = lane >> 4;

    f32x4 acc[4][4];
#pragma unroll
    for (int i = 0; i < 4; ++i)
#pragma unroll
        for (int j = 0; j < 4; ++j) acc[i][j] = (f32x4){0.f, 0.f, 0.f, 0.f};

    const int cid0 = tid, cid1 = tid + 256;     // chunk ids within a sub-tile (512 chunks)
    const int r0 = cid0 >> 2, c0 = (cid0 & 3) ^ ((r0 >> 1) & 3);
    const int r1 = cid1 >> 2, c1 = (cid1 & 3) ^ ((r1 >> 1) & 3);
    const bf16_t* Ab = A  + (size_t)bm * K + kb;
    const bf16_t* Bb = Bt + (size_t)bn * K + kb;
    const size_t ga0 = (size_t)r0 * K + c0 * 8;
    const size_t ga1 = (size_t)r1 * K + c1 * 8;
    bf16_t* ldsA0a = &Asm[wave * 512];            // sub-tile 0, chunks 0..255
    bf16_t* ldsA0b = &Asm[2048 + wave * 512];     // sub-tile 0, chunks 256..511
    bf16_t* ldsA1a = &Asm[4096 + wave * 512];     // sub-tile 1
    bf16_t* ldsA1b = &Asm[4096 + 2048 + wave * 512];
    bf16_t* ldsB0a = &Bsm[wave * 512];
    bf16_t* ldsB0b = &Bsm[2048 + wave * 512];
    bf16_t* ldsB1a = &Bsm[4096 + wave * 512];
    bf16_t* ldsB1b = &Bsm[4096 + 2048 + wave * 512];
    const int swz = (quad ^ ((lm >> 1) & 3)) * 8;

    for (int k0 = 0; k0 < kh; k0 += 64) {
        load_lds16(Ab + ga0 + k0,      ldsA0a);
        load_lds16(Ab + ga1 + k0,      ldsA0b);
        load_lds16(Ab + ga0 + k0 + 32, ldsA1a);
        load_lds16(Ab + ga1 + k0 + 32, ldsA1b);
        load_lds16(Bb + ga0 + k0,      ldsB0a);
        load_lds16(Bb + ga1 + k0,      ldsB0b);
        load_lds16(Bb + ga0 + k0 + 32, ldsB1a);
        load_lds16(Bb + ga1 + k0 + 32, ldsB1b);
        __syncthreads();
#pragma unroll
        for (int ks = 0; ks < 2; ++ks) {
            bf16x8 af[4], bfr[4];
#pragma unroll
            for (int i = 0; i < 4; ++i)
                af[i]  = *(const bf16x8*)&Asm[ks*4096 + (wm + i*16 + lm)*32 + swz];
#pragma unroll
            for (int j = 0; j < 4; ++j)
                bfr[j] = *(const bf16x8*)&Bsm[ks*4096 + (wn + j*16 + lm)*32 + swz];
#pragma unroll
            for (int i = 0; i < 4; ++i)
#pragma unroll
                for (int j = 0; j < 4; ++j) acc[i][j] = mfma16(af[i], bfr[j], acc[i][j]);
        }
        __syncthreads();
    }

    if (ATOMIC) {
#pragma unroll
        for (int i = 0; i < 4; ++i) {
            int gr = bm + wm + i*16 + quad*4;
#pragma unroll
            for (int j = 0; j < 4; ++j) {
                int gc = bn + wn + j*16 + lm;
#pragma unroll
                for (int r = 0; r < 4; ++r)
                    atomicAdd(&Cred[(size_t)(gr + r)*N + gc], acc[i][j][r]);
            }
        }
    } else {
        bf16_t* Cp = Cpart + (size_t)blockIdx.z * M * N;
#pragma unroll
        for (int i = 0; i < 4; ++i) {
            int gr = bm + wm + i*16 + quad*4;
#pragma unroll
            for (int j = 0; j < 4; ++j) {
                int gc = bn + wn + j*16 + lm;
#pragma unroll
                for (int r = 0; r < 4; ++r)
                    Cp[(size_t)(gr + r)*N + gc] = (bf16_t)acc[i][j][r];
            }
        }
    }
}

// ---------------- combine partials + bias + rope (vectorized), scatter to Q/K/V ----------
__global__ __launch_bounds__(192) void rope_split(const bf16_t* __restrict__ qp0,
                                                  const bf16_t* __restrict__ qp1,
                                                  const float* __restrict__ qbias,
                                                  const float* __restrict__ cost,
                                                  const float* __restrict__ sint,
                                                  bf16_t* __restrict__ Qb,
                                                  bf16_t* __restrict__ Kb,
                                                  bf16_t* __restrict__ Vb) {
    const int t = blockIdx.x;
    const int hr = threadIdx.x >> 2, p0 = (threadIdx.x & 3) * 8;
    const bf16_t* r0 = qp0 + (size_t)t * QKVD + hr * 64;
    const bf16_t* r1 = qp1 + (size_t)t * QKVD + hr * 64;
    bf16x8 a1 = *(const bf16x8*)(r0 + p0);
    bf16x8 a2 = *(const bf16x8*)(r0 + p0 + 32);
    bf16x8 b1 = *(const bf16x8*)(r1 + p0);
    bf16x8 b2 = *(const bf16x8*)(r1 + p0 + 32);
    const float* qb = qbias + hr * 64;
    float x1[8], x2[8];
#pragma unroll
    for (int j = 0; j < 8; ++j) {
        x1[j] = (float)a1[j] + (float)b1[j] + qb[p0 + j];
        x2[j] = (float)a2[j] + (float)b2[j] + qb[p0 + j + 32];
    }
    bf16x8 w1, w2;
    if (hr < 40) {
        const float* c = cost + (size_t)t * 32 + p0;
        const float* s = sint + (size_t)t * 32 + p0;
#pragma unroll
        for (int j = 0; j < 8; ++j) {
            float cc = c[j], ss = s[j];
            w1[j] = (bf16_t)(x1[j]*cc - x2[j]*ss);
            w2[j] = (bf16_t)(x2[j]*cc + x1[j]*ss);
        }
    } else {
#pragma unroll
        for (int j = 0; j < 8; ++j) { w1[j] = (bf16_t)x1[j]; w2[j] = (bf16_t)x2[j]; }
    }
    bf16_t* dst;
    if (hr < 32)      dst = Qb + ((size_t)t*NHEAD + hr)      * HDIM;
    else if (hr < 40) dst = Kb + ((size_t)t*NKVH + (hr-32))  * HDIM;
    else              dst = Vb + ((size_t)t*NKVH + (hr-40))  * HDIM;
    *(bf16x8*)(dst + p0)      = w1;
    *(bf16x8*)(dst + p0 + 32) = w2;
}

// ---------------- attention: direct global Q/K frags, one barrier, conflict-free Vt ------
__global__ __launch_bounds__(256) void attn_kernel(const bf16_t* __restrict__ Qb,
                                                   const bf16_t* __restrict__ Kb,
                                                   const bf16_t* __restrict__ Vb,
                                                   const float* __restrict__ sinks,
                                                   bf16_t* __restrict__ attnb) {
    __shared__ __align__(16) bf16_t Vt[64 * 200];
    __shared__ __align__(16) bf16_t Ws[64 * 200];

    const int tid = threadIdx.x;
    const int qt = blockIdx.x, h = blockIdx.y;
    const int qs = qt * 64;
    const int nkv = h >> 2;

    // V^T staging, conflict-free: lanes 0..31 of each half write 32 consecutive words.
    {
        const int off = (tid >> 5) * 8;          // dim group (fixed per thread)
#pragma unroll
        for (int it = 0; it < 3; ++it) {
            int j2 = (tid & 31) + 32 * it;       // key-pair index 0..95
            int kg0 = qs - 128 + 2*j2;     if (kg0 < 0) kg0 = 0;
            int kg1 = qs - 128 + 2*j2 + 1; if (kg1 < 0) kg1 = 0;
            union { uint4 u; bf16_t e[8]; } v0, v1;
            v0.u = *(const uint4*)(Vb + ((size_t)kg0*NKVH + nkv)*HDIM + off);
            v1.u = *(const uint4*)(Vb + ((size_t)kg1*NKVH + nkv)*HDIM + off);
#pragma unroll
            for (int r = 0; r < 8; ++r) {
                union { uint u; bf16_t e[2]; } p;
                p.e[0] = v0.e[r]; p.e[1] = v1.e[r];
                *(uint*)&Vt[(off + r)*200 + 2*j2] = p.u;
            }
        }
    }

    const int lane = tid & 63, wave = tid >> 6;
    const int lm = lane & 15, quad = lane >> 4;
    const int w16 = wave * 16;

    f32x4 S[12];
#pragma unroll
    for (int jt = 0; jt < 12; ++jt) S[jt] = (f32x4){0.f, 0.f, 0.f, 0.f};
    const bf16_t* Qrow = Qb + ((size_t)(qs + w16 + lm)*NHEAD + h)*HDIM + quad*8;
    int krow[12];
#pragma unroll
    for (int jt = 0; jt < 12; ++jt) {
        int kg = qs - 128 + jt*16 + lm;
        krow[jt] = kg < 0 ? 0 : kg;
    }
#pragma unroll
    for (int ks = 0; ks < 2; ++ks) {
        bf16x8 aq = *(const bf16x8*)(Qrow + ks*32);
#pragma unroll
        for (int jt = 0; jt < 12; ++jt) {
            bf16x8 bk = *(const bf16x8*)(Kb + ((size_t)krow[jt]*NKVH + nkv)*HDIM + ks*32 + quad*8);
            S[jt] = mfma16(aq, bk, S[jt]);
        }
    }

    const float sink = sinks[h];
#pragma unroll
    for (int reg = 0; reg < 4; ++reg) {
        const int qg = qs + w16 + quad*4 + reg;
        float mx = -1e30f;
#pragma unroll
        for (int jt = 0; jt < 12; ++jt) {
            int kg = qs - 128 + jt*16 + lm;
            float sv = S[jt][reg] * 0.125f;
            bool valid = (kg >= 0) && (kg <= qg) && (qg - kg <= 128);
            sv = valid ? sv : -1e30f;
            S[jt][reg] = sv;
            mx = fmaxf(mx, sv);
        }
#pragma unroll
        for (int off = 1; off < 16; off <<= 1) mx = fmaxf(mx, __shfl_xor(mx, off));
        float M = fmaxf(mx, sink);
        float sum = 0.f;
#pragma unroll
        for (int jt = 0; jt < 12; ++jt) {
            float e = __expf(S[jt][reg] - M);
            S[jt][reg] = e; sum += e;
        }
#pragma unroll
        for (int off = 1; off < 16; off <<= 1) sum += __shfl_xor(sum, off);
        float rden = 1.f / (sum + __expf(sink - M));
#pragma unroll
        for (int jt = 0; jt < 12; ++jt)
            Ws[(w16 + quad*4 + reg)*200 + jt*16 + lm] = (bf16_t)(S[jt][reg] * rden);
    }
    __syncthreads();

    f32x4 O[4];
#pragma unroll
    for (int nt = 0; nt < 4; ++nt) O[nt] = (f32x4){0.f, 0.f, 0.f, 0.f};
#pragma unroll
    for (int ks = 0; ks < 6; ++ks) {
        bf16x8 aw = *(const bf16x8*)&Ws[(w16 + lm)*200 + ks*32 + quad*8];
#pragma unroll
        for (int nt = 0; nt < 4; ++nt) {
            bf16x8 bv = *(const bf16x8*)&Vt[(nt*16 + lm)*200 + ks*32 + quad*8];
            O[nt] = mfma16(aw, bv, O[nt]);
        }
    }
#pragma unroll
    for (int nt = 0; nt < 4; ++nt)
#pragma unroll
        for (int reg = 0; reg < 4; ++reg)
            attnb[(size_t)(qs + w16 + quad*4 + reg)*HID + h*HDIM + nt*16 + lm] =
                (bf16_t)(O[nt][reg]);
}

// ---------------- launch ----------------
extern "C" void kernel_launch(void* const* d_in, const int* in_sizes, int n_in,
                              void* d_out, int out_size, void* d_ws, size_t ws_size,
                              hipStream_t stream) {
    (void)in_sizes; (void)n_in; (void)out_size; (void)ws_size;
    const float* x          = (const float*)d_in[0];
    const float* scale      = (const float*)d_in[1];
    const float* sinks      = (const float*)d_in[2];
    const float* qkv_kernel = (const float*)d_in[3];
    const float* qkv_bias   = (const float*)d_in[4];
    const float* out_kernel = (const float*)d_in[5];
    const float* out_bias   = (const float*)d_in[6];
    const float* cos_t      = (const float*)d_in[7];
    const float* sin_t      = (const float*)d_in[8];
    float* out = (float*)d_out;

    char* ws = (char*)d_ws;
    const size_t MiB = 1048576;
    bf16_t* Wt_out = (bf16_t*)(ws);              // [2048][2048] bf16, alive all run
    bf16_t* Wt_qkv = (bf16_t*)(ws + 8*MiB);      // [3072][2048] bf16, dead after QKV gemm
    bf16_t* attnb  = (bf16_t*)(ws + 8*MiB);      // aliases Wt_qkv
    bf16_t* normed = (bf16_t*)(ws + 20*MiB);     // [T][2048] bf16
    bf16_t* qkvp   = (bf16_t*)(ws + 28*MiB);     // [2][T][3072] bf16
    bf16_t* Qb     = (bf16_t*)(ws + 52*MiB);
    bf16_t* Kb     = (bf16_t*)(ws + 60*MiB);
    bf16_t* Vb     = (bf16_t*)(ws + 62*MiB);

    prep_kernel<<<4608, 256, 0, stream>>>(qkv_kernel, out_kernel, Wt_qkv, Wt_out,
                                          x, scale, normed, out_bias, out);
    gemm_splitk<0><<<dim3(QKVD/128, T_SEQ/128, 2), 256, 0, stream>>>(normed, Wt_qkv, qkvp,
                                                                     nullptr, T_SEQ, QKVD, HID);
    rope_split<<<T_SEQ, 192, 0, stream>>>(qkvp, qkvp + (size_t)T_SEQ*QKVD, qkv_bias,
                                          cos_t, sin_t, Qb, Kb, Vb);
    attn_kernel<<<dim3(T_SEQ/64, NHEAD), 256, 0, stream>>>(Qb, Kb, Vb, sinks, attnb);
    gemm_splitk<1><<<dim3(HID/128, T_SEQ/128, 2), 256, 0, stream>>>(attnb, Wt_out, nullptr,
                                                                    out, T_SEQ, HID, HID);
}

// Round 7
// 221.495 us; speedup vs baseline: 1.0724x; 1.0436x over previous
//
#include <hip/hip_runtime.h>
#include <hip/hip_bf16.h>
#include <stdint.h>

typedef __bf16 bf16_t;
typedef __attribute__((ext_vector_type(8))) __bf16 bf16x8;
typedef __attribute__((ext_vector_type(4))) __bf16 bf16x4;
typedef __attribute__((ext_vector_type(4))) float f32x4;

static constexpr int T_SEQ = 2048;
static constexpr int HID   = 2048;
static constexpr int NHEAD = 32;
static constexpr int NKVH  = 8;
static constexpr int HDIM  = 64;
static constexpr int QKVD  = 3072;   // 64*(32+16)

__device__ inline f32x4 mfma16(bf16x8 a, bf16x8 b, f32x4 c) {
    return __builtin_amdgcn_mfma_f32_16x16x32_bf16(a, b, c, 0, 0, 0);
}

__device__ inline void load_lds16(const bf16_t* g, bf16_t* l) {
    __builtin_amdgcn_global_load_lds(
        (const __attribute__((address_space(1))) void*)g,
        (__attribute__((address_space(3))) void*)l, 16, 0, 0);
}

// ---------------- prep: weight transposes + RMSNorm (one dispatch) ----------------
// blocks [0,1536): Wq transpose; [1536,2560): Wo transpose; [2560,4608): rmsnorm rows.
__global__ __launch_bounds__(256) void prep_kernel(const float* __restrict__ Wq,
                                                   const float* __restrict__ Wo,
                                                   bf16_t* __restrict__ Tq,
                                                   bf16_t* __restrict__ To,
                                                   const float* __restrict__ x,
                                                   const float* __restrict__ scale,
                                                   bf16_t* __restrict__ normed) {
    __shared__ float tile[64 * 65];
    int b = blockIdx.x;
    const int t = threadIdx.x;
    if (b < 2560) {
        const float* in; bf16_t* outw; int NN, KK, bx, by;
        if (b < 1536) { in = Wq; outw = Tq; NN = QKVD; KK = HID; bx = b % 48; by = b / 48; }
        else { b -= 1536; in = Wo; outw = To; NN = HID; KK = HID; bx = b % 32; by = b / 32; }
        const int c4 = (t & 15) * 4;
#pragma unroll
        for (int i = 0; i < 4; ++i) {
            int r = (t >> 4) + i * 16;
            float4 v = *(const float4*)(in + (size_t)(by*64 + r) * NN + bx*64 + c4);
            tile[r*65 + c4 + 0] = v.x; tile[r*65 + c4 + 1] = v.y;
            tile[r*65 + c4 + 2] = v.z; tile[r*65 + c4 + 3] = v.w;
        }
        __syncthreads();
        const int kc = t & 7;
#pragma unroll
        for (int i = 0; i < 2; ++i) {
            int n = (t >> 3) + i * 32;
            bf16x8 o;
#pragma unroll
            for (int j = 0; j < 8; ++j) o[j] = (bf16_t)tile[(kc*8 + j)*65 + n];
            *(bf16x8*)(outw + (size_t)(bx*64 + n) * KK + by*64 + kc*8) = o;
        }
    } else {
        int row = b - 2560;
        const float4* x4 = (const float4*)(x + (size_t)row * HID);
        const float4* s4 = (const float4*)scale;
        float4 v0 = x4[t], v1 = x4[t + 256];
        float ss = v0.x*v0.x + v0.y*v0.y + v0.z*v0.z + v0.w*v0.w
                 + v1.x*v1.x + v1.y*v1.y + v1.z*v1.z + v1.w*v1.w;
#pragma unroll
        for (int off = 32; off > 0; off >>= 1) ss += __shfl_down(ss, off);
        if ((t & 63) == 0) tile[t >> 6] = ss;
        __syncthreads();
        float total = tile[0] + tile[1] + tile[2] + tile[3];
        float inv = rsqrtf(total * (1.0f / HID) + 1e-5f);
        float4 sc0 = s4[t], sc1 = s4[t + 256];
        bf16_t* outr = normed + (size_t)row * HID;
        bf16x4 o0, o1;
        o0.x = (bf16_t)(v0.x*inv*sc0.x); o0.y = (bf16_t)(v0.y*inv*sc0.y);
        o0.z = (bf16_t)(v0.z*inv*sc0.z); o0.w = (bf16_t)(v0.w*inv*sc0.w);
        o1.x = (bf16_t)(v1.x*inv*sc1.x); o1.y = (bf16_t)(v1.y*inv*sc1.y);
        o1.z = (bf16_t)(v1.z*inv*sc1.z); o1.w = (bf16_t)(v1.w*inv*sc1.w);
        *(bf16x4*)(outr + 4*t)        = o0;
        *(bf16x4*)(outr + 1024 + 4*t) = o1;
    }
}

// ---------------- split-K GEMM, 128x128 tile, BK=64 (round-6 verified core) ----------
// Each 32-k sub-tile uses the round-2 verified conflict-free geometry: LDS chunk j
// holds global chunk (r=j>>2, c=(j&3)^((r>>1)&3)); frag read offset (quad^((lm>>1)&3))*8.
// bf16 partials to Cpart[z][M][N]; downstream kernel combines.
__global__ __launch_bounds__(256) void gemm_splitk(const bf16_t* __restrict__ A,
                                                   const bf16_t* __restrict__ Bt,
                                                   bf16_t* __restrict__ Cpart,
                                                   int M, int N, int K) {
    __shared__ __align__(16) bf16_t Asm[2 * 128 * 32];   // 16 KB
    __shared__ __align__(16) bf16_t Bsm[2 * 128 * 32];   // 16 KB
    const int tid = threadIdx.x;
    const int bm = blockIdx.y * 128, bn = blockIdx.x * 128;
    const int kh = K >> 1;
    const int kb = blockIdx.z * kh;
    const int lane = tid & 63, wave = tid >> 6;
    const int wm = (wave & 1) * 64, wn = (wave >> 1) * 64;
    const int lm = lane & 15, quad = lane >> 4;

    f32x4 acc[4][4];
#pragma unroll
    for (int i = 0; i < 4; ++i)
#pragma unroll
        for (int j = 0; j < 4; ++j) acc[i][j] = (f32x4){0.f, 0.f, 0.f, 0.f};

    const int cid0 = tid, cid1 = tid + 256;
    const int r0 = cid0 >> 2, c0 = (cid0 & 3) ^ ((r0 >> 1) & 3);
    const int r1 = cid1 >> 2, c1 = (cid1 & 3) ^ ((r1 >> 1) & 3);
    const bf16_t* Ab = A  + (size_t)bm * K + kb;
    const bf16_t* Bb = Bt + (size_t)bn * K + kb;
    const size_t ga0 = (size_t)r0 * K + c0 * 8;
    const size_t ga1 = (size_t)r1 * K + c1 * 8;
    bf16_t* ldsA0a = &Asm[wave * 512];
    bf16_t* ldsA0b = &Asm[2048 + wave * 512];
    bf16_t* ldsA1a = &Asm[4096 + wave * 512];
    bf16_t* ldsA1b = &Asm[4096 + 2048 + wave * 512];
    bf16_t* ldsB0a = &Bsm[wave * 512];
    bf16_t* ldsB0b = &Bsm[2048 + wave * 512];
    bf16_t* ldsB1a = &Bsm[4096 + wave * 512];
    bf16_t* ldsB1b = &Bsm[4096 + 2048 + wave * 512];
    const int swz = (quad ^ ((lm >> 1) & 3)) * 8;

    for (int k0 = 0; k0 < kh; k0 += 64) {
        load_lds16(Ab + ga0 + k0,      ldsA0a);
        load_lds16(Ab + ga1 + k0,      ldsA0b);
        load_lds16(Ab + ga0 + k0 + 32, ldsA1a);
        load_lds16(Ab + ga1 + k0 + 32, ldsA1b);
        load_lds16(Bb + ga0 + k0,      ldsB0a);
        load_lds16(Bb + ga1 + k0,      ldsB0b);
        load_lds16(Bb + ga0 + k0 + 32, ldsB1a);
        load_lds16(Bb + ga1 + k0 + 32, ldsB1b);
        __syncthreads();
#pragma unroll
        for (int ks = 0; ks < 2; ++ks) {
            bf16x8 af[4], bfr[4];
#pragma unroll
            for (int i = 0; i < 4; ++i)
                af[i]  = *(const bf16x8*)&Asm[ks*4096 + (wm + i*16 + lm)*32 + swz];
#pragma unroll
            for (int j = 0; j < 4; ++j)
                bfr[j] = *(const bf16x8*)&Bsm[ks*4096 + (wn + j*16 + lm)*32 + swz];
#pragma unroll
            for (int i = 0; i < 4; ++i)
#pragma unroll
                for (int j = 0; j < 4; ++j) acc[i][j] = mfma16(af[i], bfr[j], acc[i][j]);
        }
        __syncthreads();
    }

    bf16_t* Cp = Cpart + (size_t)blockIdx.z * M * N;
#pragma unroll
    for (int i = 0; i < 4; ++i) {
        int gr = bm + wm + i*16 + quad*4;
#pragma unroll
        for (int j = 0; j < 4; ++j) {
            int gc = bn + wn + j*16 + lm;
#pragma unroll
            for (int r = 0; r < 4; ++r)
                Cp[(size_t)(gr + r)*N + gc] = (bf16_t)acc[i][j][r];
        }
    }
}

// ---------------- combine partials + bias + rope (vectorized), scatter to Q/K/V ----------
__global__ __launch_bounds__(192) void rope_split(const bf16_t* __restrict__ qp0,
                                                  const bf16_t* __restrict__ qp1,
                                                  const float* __restrict__ qbias,
                                                  const float* __restrict__ cost,
                                                  const float* __restrict__ sint,
                                                  bf16_t* __restrict__ Qb,
                                                  bf16_t* __restrict__ Kb,
                                                  bf16_t* __restrict__ Vb) {
    const int t = blockIdx.x;
    const int hr = threadIdx.x >> 2, p0 = (threadIdx.x & 3) * 8;
    const bf16_t* r0 = qp0 + (size_t)t * QKVD + hr * 64;
    const bf16_t* r1 = qp1 + (size_t)t * QKVD + hr * 64;
    bf16x8 a1 = *(const bf16x8*)(r0 + p0);
    bf16x8 a2 = *(const bf16x8*)(r0 + p0 + 32);
    bf16x8 b1 = *(const bf16x8*)(r1 + p0);
    bf16x8 b2 = *(const bf16x8*)(r1 + p0 + 32);
    const float* qb = qbias + hr * 64;
    float x1[8], x2[8];
#pragma unroll
    for (int j = 0; j < 8; ++j) {
        x1[j] = (float)a1[j] + (float)b1[j] + qb[p0 + j];
        x2[j] = (float)a2[j] + (float)b2[j] + qb[p0 + j + 32];
    }
    bf16x8 w1, w2;
    if (hr < 40) {
        const float* c = cost + (size_t)t * 32 + p0;
        const float* s = sint + (size_t)t * 32 + p0;
#pragma unroll
        for (int j = 0; j < 8; ++j) {
            float cc = c[j], ss = s[j];
            w1[j] = (bf16_t)(x1[j]*cc - x2[j]*ss);
            w2[j] = (bf16_t)(x2[j]*cc + x1[j]*ss);
        }
    } else {
#pragma unroll
        for (int j = 0; j < 8; ++j) { w1[j] = (bf16_t)x1[j]; w2[j] = (bf16_t)x2[j]; }
    }
    bf16_t* dst;
    if (hr < 32)      dst = Qb + ((size_t)t*NHEAD + hr)      * HDIM;
    else if (hr < 40) dst = Kb + ((size_t)t*NKVH + (hr-32))  * HDIM;
    else              dst = Vb + ((size_t)t*NKVH + (hr-40))  * HDIM;
    *(bf16x8*)(dst + p0)      = w1;
    *(bf16x8*)(dst + p0 + 32) = w2;
}

// ---------------- combine out-proj partials + bias + residual ----------------
__global__ __launch_bounds__(256) void combine_out(const bf16_t* __restrict__ p0,
                                                   const bf16_t* __restrict__ p1,
                                                   const float* __restrict__ bias,
                                                   const float* __restrict__ x,
                                                   float* __restrict__ out) {
    const int n4 = T_SEQ * HID / 4;
    for (int i4 = blockIdx.x * 256 + threadIdx.x; i4 < n4; i4 += gridDim.x * 256) {
        bf16x4 a = *(const bf16x4*)(p0 + (size_t)i4 * 4);
        bf16x4 b = *(const bf16x4*)(p1 + (size_t)i4 * 4);
        float4 xv = *(const float4*)(x + (size_t)i4 * 4);
        int col4 = (i4 * 4) & (HID - 1);
        float4 bi = *(const float4*)(bias + col4);
        float4 o;
        o.x = (float)a.x + (float)b.x + bi.x + xv.x;
        o.y = (float)a.y + (float)b.y + bi.y + xv.y;
        o.z = (float)a.z + (float)b.z + bi.z + xv.z;
        o.w = (float)a.w + (float)b.w + bi.w + xv.w;
        *(float4*)(out + (size_t)i4 * 4) = o;
    }
}

// ---------------- attention: direct global Q/K frags, one barrier, conflict-free Vt ------
__global__ __launch_bounds__(256) void attn_kernel(const bf16_t* __restrict__ Qb,
                                                   const bf16_t* __restrict__ Kb,
                                                   const bf16_t* __restrict__ Vb,
                                                   const float* __restrict__ sinks,
                                                   bf16_t* __restrict__ attnb) {
    __shared__ __align__(16) bf16_t Vt[64 * 200];
    __shared__ __align__(16) bf16_t Ws[64 * 200];

    const int tid = threadIdx.x;
    const int qt = blockIdx.x, h = blockIdx.y;
    const int qs = qt * 64;
    const int nkv = h >> 2;

    // V^T staging, conflict-free: lanes 0..31 of each half write 32 consecutive words.
    {
        const int off = (tid >> 5) * 8;
#pragma unroll
        for (int it = 0; it < 3; ++it) {
            int j2 = (tid & 31) + 32 * it;
            int kg0 = qs - 128 + 2*j2;     if (kg0 < 0) kg0 = 0;
            int kg1 = qs - 128 + 2*j2 + 1; if (kg1 < 0) kg1 = 0;
            union { uint4 u; bf16_t e[8]; } v0, v1;
            v0.u = *(const uint4*)(Vb + ((size_t)kg0*NKVH + nkv)*HDIM + off);
            v1.u = *(const uint4*)(Vb + ((size_t)kg1*NKVH + nkv)*HDIM + off);
#pragma unroll
            for (int r = 0; r < 8; ++r) {
                union { uint u; bf16_t e[2]; } p;
                p.e[0] = v0.e[r]; p.e[1] = v1.e[r];
                *(uint*)&Vt[(off + r)*200 + 2*j2] = p.u;
            }
        }
    }

    const int lane = tid & 63, wave = tid >> 6;
    const int lm = lane & 15, quad = lane >> 4;
    const int w16 = wave * 16;

    f32x4 S[12];
#pragma unroll
    for (int jt = 0; jt < 12; ++jt) S[jt] = (f32x4){0.f, 0.f, 0.f, 0.f};
    const bf16_t* Qrow = Qb + ((size_t)(qs + w16 + lm)*NHEAD + h)*HDIM + quad*8;
    int krow[12];
#pragma unroll
    for (int jt = 0; jt < 12; ++jt) {
        int kg = qs - 128 + jt*16 + lm;
        krow[jt] = kg < 0 ? 0 : kg;
    }
#pragma unroll
    for (int ks = 0; ks < 2; ++ks) {
        bf16x8 aq = *(const bf16x8*)(Qrow + ks*32);
#pragma unroll
        for (int jt = 0; jt < 12; ++jt) {
            bf16x8 bk = *(const bf16x8*)(Kb + ((size_t)krow[jt]*NKVH + nkv)*HDIM + ks*32 + quad*8);
            S[jt] = mfma16(aq, bk, S[jt]);
        }
    }

    const float sink = sinks[h];
#pragma unroll
    for (int reg = 0; reg < 4; ++reg) {
        const int qg = qs + w16 + quad*4 + reg;
        float mx = -1e30f;
#pragma unroll
        for (int jt = 0; jt < 12; ++jt) {
            int kg = qs - 128 + jt*16 + lm;
            float sv = S[jt][reg] * 0.125f;
            bool valid = (kg >= 0) && (kg <= qg) && (qg - kg <= 128);
            sv = valid ? sv : -1e30f;
            S[jt][reg] = sv;
            mx = fmaxf(mx, sv);
        }
#pragma unroll
        for (int off = 1; off < 16; off <<= 1) mx = fmaxf(mx, __shfl_xor(mx, off));
        float M = fmaxf(mx, sink);
        float sum = 0.f;
#pragma unroll
        for (int jt = 0; jt < 12; ++jt) {
            float e = __expf(S[jt][reg] - M);
            S[jt][reg] = e; sum += e;
        }
#pragma unroll
        for (int off = 1; off < 16; off <<= 1) sum += __shfl_xor(sum, off);
        float rden = 1.f / (sum + __expf(sink - M));
#pragma unroll
        for (int jt = 0; jt < 12; ++jt)
            Ws[(w16 + quad*4 + reg)*200 + jt*16 + lm] = (bf16_t)(S[jt][reg] * rden);
    }
    __syncthreads();

    f32x4 O[4];
#pragma unroll
    for (int nt = 0; nt < 4; ++nt) O[nt] = (f32x4){0.f, 0.f, 0.f, 0.f};
#pragma unroll
    for (int ks = 0; ks < 6; ++ks) {
        bf16x8 aw = *(const bf16x8*)&Ws[(w16 + lm)*200 + ks*32 + quad*8];
#pragma unroll
        for (int nt = 0; nt < 4; ++nt) {
            bf16x8 bv = *(const bf16x8*)&Vt[(nt*16 + lm)*200 + ks*32 + quad*8];
            O[nt] = mfma16(aw, bv, O[nt]);
        }
    }
#pragma unroll
    for (int nt = 0; nt < 4; ++nt)
#pragma unroll
        for (int reg = 0; reg < 4; ++reg)
            attnb[(size_t)(qs + w16 + quad*4 + reg)*HID + h*HDIM + nt*16 + lm] =
                (bf16_t)(O[nt][reg]);
}

// ---------------- launch ----------------
extern "C" void kernel_launch(void* const* d_in, const int* in_sizes, int n_in,
                              void* d_out, int out_size, void* d_ws, size_t ws_size,
                              hipStream_t stream) {
    (void)in_sizes; (void)n_in; (void)out_size; (void)ws_size;
    const float* x          = (const float*)d_in[0];
    const float* scale      = (const float*)d_in[1];
    const float* sinks      = (const float*)d_in[2];
    const float* qkv_kernel = (const float*)d_in[3];
    const float* qkv_bias   = (const float*)d_in[4];
    const float* out_kernel = (const float*)d_in[5];
    const float* out_bias   = (const float*)d_in[6];
    const float* cos_t      = (const float*)d_in[7];
    const float* sin_t      = (const float*)d_in[8];
    float* out = (float*)d_out;

    // ws plan (64 MiB, aliasing by liveness):
    //   [ 0, 8)   Wt_out  bf16 [2048][2048]  (alive all run)
    //   [ 8,20)   Wt_qkv  bf16 [3072][2048]  (dead after QKV gemm)
    //   [ 8,16)   attnb   bf16 [T][2048]     (aliases Wt_qkv)
    //   [20,28)   normed  bf16 [T][2048]
    //   [28,52)   qkvp    bf16 [2][T][3072]  (dead after rope)
    //   [28,44)   outp    bf16 [2][T][2048]  (aliases qkvp)
    //   [52,64)   Qb/Kb/Vb bf16
    char* ws = (char*)d_ws;
    const size_t MiB = 1048576;
    bf16_t* Wt_out = (bf16_t*)(ws);
    bf16_t* Wt_qkv = (bf16_t*)(ws + 8*MiB);
    bf16_t* attnb  = (bf16_t*)(ws + 8*MiB);
    bf16_t* normed = (bf16_t*)(ws + 20*MiB);
    bf16_t* qkvp   = (bf16_t*)(ws + 28*MiB);
    bf16_t* outp   = (bf16_t*)(ws + 28*MiB);
    bf16_t* Qb     = (bf16_t*)(ws + 52*MiB);
    bf16_t* Kb     = (bf16_t*)(ws + 60*MiB);
    bf16_t* Vb     = (bf16_t*)(ws + 62*MiB);

    prep_kernel<<<4608, 256, 0, stream>>>(qkv_kernel, out_kernel, Wt_qkv, Wt_out,
                                          x, scale, normed);
    gemm_splitk<<<dim3(QKVD/128, T_SEQ/128, 2), 256, 0, stream>>>(normed, Wt_qkv, qkvp,
                                                                  T_SEQ, QKVD, HID);
    rope_split<<<T_SEQ, 192, 0, stream>>>(qkvp, qkvp + (size_t)T_SEQ*QKVD, qkv_bias,
                                          cos_t, sin_t, Qb, Kb, Vb);
    attn_kernel<<<dim3(T_SEQ/64, NHEAD), 256, 0, stream>>>(Qb, Kb, Vb, sinks, attnb);
    gemm_splitk<<<dim3(HID/128, T_SEQ/128, 2), 256, 0, stream>>>(attnb, Wt_out, outp,
                                                                 T_SEQ, HID, HID);
    combine_out<<<2048, 256, 0, stream>>>(outp, outp + (size_t)T_SEQ*HID, out_bias, x, out);
}